// Round 1
// baseline (2079.867 us; speedup 1.0000x reference)
//
#include <hip/hip_runtime.h>
#include <math.h>

#define B 2
#define S 1024
#define E 2048
#define H 16
#define HD 128
#define ROT 64
#define EPSN 1e-12f

// ---------------------------------------------------------------------------
// NT-GEMM: C[m,n] = sum_k A[m,k] * W[n,k].  M,N,K multiples of 64.
// 64x64 tile, BK=16, 256 threads, 4x4 acc per thread.
// ---------------------------------------------------------------------------
__global__ __launch_bounds__(256) void gemm_nt(const float* __restrict__ A,
                                               const float* __restrict__ W,
                                               float* __restrict__ C,
                                               int M, int N, int K) {
    __shared__ float As[16][68];   // [k][m], pad 68 keeps float4 reads aligned, banks spread
    __shared__ float Ws[16][68];   // [k][n]
    const int tid = threadIdx.x;
    const int tx = tid & 15;       // n-group
    const int ty = tid >> 4;       // m-group
    const int mBase = blockIdx.y * 64;
    const int nBase = blockIdx.x * 64;

    float acc[4][4] = {};

    for (int k0 = 0; k0 < K; k0 += 16) {
#pragma unroll
        for (int j = 0; j < 4; ++j) {
            int f = tid + j * 256;          // 0..1023 over 64x16 tile
            int r = f >> 4;                 // row within tile
            int c = f & 15;                 // k within tile
            As[c][r] = A[(size_t)(mBase + r) * K + k0 + c];
            Ws[c][r] = W[(size_t)(nBase + r) * K + k0 + c];
        }
        __syncthreads();
#pragma unroll
        for (int kk = 0; kk < 16; ++kk) {
            float4 a4 = *reinterpret_cast<const float4*>(&As[kk][ty * 4]);
            float4 w4 = *reinterpret_cast<const float4*>(&Ws[kk][tx * 4]);
            float a[4] = {a4.x, a4.y, a4.z, a4.w};
            float w[4] = {w4.x, w4.y, w4.z, w4.w};
#pragma unroll
            for (int i = 0; i < 4; ++i)
#pragma unroll
                for (int j = 0; j < 4; ++j)
                    acc[i][j] += a[i] * w[j];
        }
        __syncthreads();
    }

#pragma unroll
    for (int i = 0; i < 4; ++i) {
        size_t off = (size_t)(mBase + ty * 4 + i) * N + nBase + tx * 4;
        float4 v = make_float4(acc[i][0], acc[i][1], acc[i][2], acc[i][3]);
        *reinterpret_cast<float4*>(&C[off]) = v;
    }
}

// ---------------------------------------------------------------------------
// counts[b][s] = # of valid (mask==0) positions <= s   (serial scan, trivial)
// ---------------------------------------------------------------------------
__global__ void counts_kernel(const float* __restrict__ am, float* __restrict__ counts) {
    int b = blockIdx.x;
    float run = 0.f;
    for (int s = 0; s < S; ++s) {
        run += (am[b * S + s] == 0.f) ? 1.f : 0.f;
        counts[b * S + s] = run;
    }
}

// ---------------------------------------------------------------------------
// Rotary (first ROT dims, rotate-every-two) + L2 normalize (all HD dims)
// + mask zeroing. One wave per (b,s,h); lane l handles dims 2l, 2l+1.
// Applied in-place to q and k.
// ---------------------------------------------------------------------------
__global__ __launch_bounds__(256) void rotary_norm(float* __restrict__ qb,
                                                   float* __restrict__ kb,
                                                   const float* __restrict__ am,
                                                   const int* __restrict__ pos) {
    const int wave = threadIdx.x >> 6;
    const int lane = threadIdx.x & 63;
    const int item = blockIdx.x * 4 + wave;      // < B*S*H
    const int b = item / (S * H);
    const int s = (item / H) % S;
    const int h = item % H;

    const float p = (float)pos[b * S + s];
    float co = 1.f, si = 0.f;
    if (lane < 32) {
        // inv_freq[j] = 10000^(-j/32),  j = lane
        float ang = p * expf(-0.28782313662425574f * (float)lane); // ln(10000)/32
        sincosf(ang, &si, &co);
    }
    const float valid = (am[b * S + s] == 0.f) ? 1.f : 0.f;
    const size_t base = (size_t)(b * S + s) * E + h * HD;

    float* bufs[2] = {qb, kb};
#pragma unroll
    for (int a = 0; a < 2; ++a) {
        float* ptr = bufs[a];
        float x0 = ptr[base + 2 * lane];
        float x1 = ptr[base + 2 * lane + 1];
        float y0, y1;
        if (lane < 32) {   // rotary on dims < 64
            y0 = x0 * co - x1 * si;
            y1 = x1 * co + x0 * si;
        } else {
            y0 = x0;
            y1 = x1;
        }
        float ss = y0 * y0 + y1 * y1;
#pragma unroll
        for (int off = 32; off > 0; off >>= 1)
            ss += __shfl_xor(ss, off);
        float scale = valid / fmaxf(sqrtf(ss), EPSN);
        ptr[base + 2 * lane]     = y0 * scale;
        ptr[base + 2 * lane + 1] = y1 * scale;
    }
}

// ---------------------------------------------------------------------------
// v[b,s,h,d] *= mask(b,s) / max(counts[b,s]^sigmoid(nc[h]), 1)
// ---------------------------------------------------------------------------
__global__ __launch_bounds__(256) void vscale(float* __restrict__ v,
                                              const float* __restrict__ am,
                                              const float* __restrict__ counts,
                                              const float* __restrict__ nc) {
    int idx = blockIdx.x * 256 + threadIdx.x;    // < B*S*E
    int b = idx / (S * E);
    int rem = idx % (S * E);
    int s = rem / E;
    int h = (rem % E) / HD;
    float sig = 1.f / (1.f + expf(-nc[h]));
    float cnt = counts[b * S + s];
    float denom = fmaxf(powf(cnt, sig), 1.f);
    float m = (am[b * S + s] == 0.f) ? 1.f : 0.f;
    v[idx] = v[idx] * m / denom;
}

// ---------------------------------------------------------------------------
// Attention per (b,h): O = tril(Qn Kn^T) @ Vs.  No softmax.
// Block: 32-query tile x full HD=128.  K chunks of 32.
// q/k/v/o all laid out (b, s, h, d)  [i.e. (b*S+s)*E + h*HD + d]
// ---------------------------------------------------------------------------
__global__ __launch_bounds__(256) void attn(const float* __restrict__ q,
                                            const float* __restrict__ k,
                                            const float* __restrict__ v,
                                            float* __restrict__ o) {
    __shared__ float Qs[32][132];
    __shared__ float Ks[32][132];
    __shared__ float Vs[32][132];
    __shared__ float Ss[32][33];

    const int qt = blockIdx.x;           // query tile 0..31
    const int bh = blockIdx.y;           // 0..B*H-1
    const int b = bh / H, h = bh % H;
    const int tid = threadIdx.x;
    const int qBase = qt * 32;

#pragma unroll
    for (int j = 0; j < 16; ++j) {
        int f = tid + j * 256;           // over 32x128
        int r = f >> 7, c = f & 127;
        Qs[r][c] = q[(size_t)(b * S + qBase + r) * E + h * HD + c];
    }

    const int ql = tid >> 3;             // 0..31 query row
    const int g  = tid & 7;              // 0..7  (k-group for scores, d-group for PV)
    float acc[16] = {};

    for (int kc = 0; kc <= qt; ++kc) {
        const int kBase = kc * 32;
#pragma unroll
        for (int j = 0; j < 16; ++j) {
            int f = tid + j * 256;
            int r = f >> 7, c = f & 127;
            Ks[r][c] = k[(size_t)(b * S + kBase + r) * E + h * HD + c];
            Vs[r][c] = v[(size_t)(b * S + kBase + r) * E + h * HD + c];
        }
        __syncthreads();

        // scores: 4 per thread
#pragma unroll
        for (int kk = 0; kk < 4; ++kk) {
            int kl = g * 4 + kk;
            float dot = 0.f;
#pragma unroll
            for (int i = 0; i < 32; ++i) {
                float4 qa = *reinterpret_cast<const float4*>(&Qs[ql][i * 4]);
                float4 ka = *reinterpret_cast<const float4*>(&Ks[kl][i * 4]);
                dot += qa.x * ka.x + qa.y * ka.y + qa.z * ka.z + qa.w * ka.w;
            }
            Ss[ql][kl] = (kBase + kl <= qBase + ql) ? dot : 0.f;
        }
        __syncthreads();

        // PV: thread (ql, dims g*16..g*16+15)
#pragma unroll
        for (int kl = 0; kl < 32; ++kl) {
            float sv = Ss[ql][kl];
            const float4* vp = reinterpret_cast<const float4*>(&Vs[kl][g * 16]);
#pragma unroll
            for (int d4 = 0; d4 < 4; ++d4) {
                float4 vv = vp[d4];
                acc[d4 * 4 + 0] += sv * vv.x;
                acc[d4 * 4 + 1] += sv * vv.y;
                acc[d4 * 4 + 2] += sv * vv.z;
                acc[d4 * 4 + 3] += sv * vv.w;
            }
        }
        __syncthreads();
    }

    size_t off = (size_t)(b * S + qBase + ql) * E + h * HD + g * 16;
#pragma unroll
    for (int d4 = 0; d4 < 4; ++d4) {
        float4 vv = make_float4(acc[d4 * 4 + 0], acc[d4 * 4 + 1],
                                acc[d4 * 4 + 2], acc[d4 * 4 + 3]);
        *reinterpret_cast<float4*>(&o[off + d4 * 4]) = vv;
    }
}

// ---------------------------------------------------------------------------
extern "C" void kernel_launch(void* const* d_in, const int* in_sizes, int n_in,
                              void* d_out, int out_size, void* d_ws, size_t ws_size,
                              hipStream_t stream) {
    (void)in_sizes; (void)n_in; (void)out_size; (void)ws_size;
    const float* hs = (const float*)d_in[0];
    const float* wq = (const float*)d_in[1];
    const float* wk = (const float*)d_in[2];
    const float* wv = (const float*)d_in[3];
    const float* wo = (const float*)d_in[4];
    const float* nc = (const float*)d_in[5];
    const float* am = (const float*)d_in[6];
    const int*  pos = (const int*)d_in[7];
    float* out = (float*)d_out;

    const size_t act = (size_t)B * S * E;     // 4,194,304 floats
    float* qb  = (float*)d_ws;
    float* kb  = qb + act;
    float* vb  = kb + act;
    float* ab  = vb + act;
    float* cnt = ab + act;                    // B*S floats

    dim3 ggrid(E / 64, (B * S) / 64);
    gemm_nt<<<ggrid, 256, 0, stream>>>(hs, wq, qb, B * S, E, E);
    gemm_nt<<<ggrid, 256, 0, stream>>>(hs, wk, kb, B * S, E, E);
    gemm_nt<<<ggrid, 256, 0, stream>>>(hs, wv, vb, B * S, E, E);
    counts_kernel<<<B, 1, 0, stream>>>(am, cnt);
    rotary_norm<<<(B * S * H) / 4, 256, 0, stream>>>(qb, kb, am, pos);
    vscale<<<(B * S * E) / 256, 256, 0, stream>>>(vb, am, cnt, nc);
    attn<<<dim3(S / 32, B * H), 256, 0, stream>>>(qb, kb, vb, ab);
    gemm_nt<<<ggrid, 256, 0, stream>>>(ab, wo, out, B * S, E, E);
}